// Round 7
// baseline (686.795 us; speedup 1.0000x reference)
//
#include <hip/hip_runtime.h>

#define N_NODES 10000
#define N_EDGES 160000

typedef unsigned short u16;
typedef unsigned int   u32;
typedef __bf16 bf16x8 __attribute__((ext_vector_type(8)));
typedef float  f32x4  __attribute__((ext_vector_type(4)));
typedef unsigned short u16x4 __attribute__((ext_vector_type(4)));

struct InP { const void* p[22]; };

// ---------------- workspace layout (bytes) ----------------
static constexpr size_t WS_WK1T = 0;                        // bf16 4096  frag-packed
static constexpr size_t WS_WK2T = WS_WK1T + 8192;           // bf16 16384
static constexpr size_t WS_WK3T = WS_WK2T + 32768;          // bf16 65536
static constexpr size_t WS_WV1T = WS_WK3T + 131072;         // bf16 4096
static constexpr size_t WS_WV2T = WS_WV1T + 8192;           // bf16 16384
static constexpr size_t WS_WV3T = WS_WV2T + 32768;          // bf16 131072
static constexpr size_t WS_T    = WS_WV3T + 262144;         // f32 [N][16]
static constexpr size_t WS_Q    = WS_T    + (size_t)N_NODES*16*4;  // f32 [N][8]
static constexpr size_t WS_Z    = WS_Q    + (size_t)N_NODES*8*4;   // f32 [N]
static constexpr size_t WS_AGG  = WS_Z    + (size_t)N_NODES*4;     // f32 [N][16]
static constexpr size_t WS_BNS  = WS_AGG  + (size_t)N_NODES*16*4;  // f32 64
static constexpr size_t WS_BNQ  = WS_BNS  + 256;
static constexpr size_t WS_OUTP = WS_BNQ  + 256;            // f32 [N][64]
static constexpr size_t ZERO_OFF = WS_Z;
static constexpr size_t ZERO_LEN = WS_OUTP - WS_Z;

// ---------------- helpers ----------------
__device__ __forceinline__ int detect_isbf(const void* ed){
  int lane = threadIdx.x & 63;
  u16 v = ((const u16*)ed)[lane*2];
  int ex = (v >> 7) & 0xFF;
  unsigned long long b = __ballot(ex >= 100 && ex <= 140);
  return __popcll(b) >= 48;
}
__device__ __forceinline__ float loadf(const void* p, long i, int isbf){
  if(isbf){
    u32 x = ((u32)((const u16*)p)[i]) << 16;
    return __uint_as_float(x);
  }
  return ((const float*)p)[i];
}
__device__ __forceinline__ f32x4 loadf4(const void* p, long i, int isbf){
  if(isbf){
    u16x4 v = *(const u16x4*)((const u16*)p + i);
    f32x4 r;
    #pragma unroll
    for(int k=0;k<4;k++) r[k] = __uint_as_float(((u32)v[k])<<16);
    return r;
  }
  return *(const f32x4*)((const float*)p + i);
}
__device__ __forceinline__ u16 f2b(float f){
  u32 u = __float_as_uint(f);
  u += 0x7fffu + ((u >> 16) & 1u);
  return (u16)(u >> 16);
}
__device__ __forceinline__ float b2f(u16 v){
  return __uint_as_float(((u32)v) << 16);
}
__device__ __forceinline__ bf16x8 ld8(const u16* p){
  uint4 v = *(const uint4*)p;
  return __builtin_bit_cast(bf16x8, v);
}

// ---------------- k_pre: weight frag-packing + per-node t/q ----------------
// phys g: i=g&7; l=(g>>3)&63; r2=g>>9; kk=r2%nk; c16=r2/nk;
// n=c16*16+(l&15); k=kk*32+(l>>4)*8+i; src=W[k][n]   (r3-verified)
__global__ void k_pre(InP in, char* ws){
  const int isbf = detect_isbf(in.p[2]);
  int bi = blockIdx.x;
  if(bi < 928){
    long g = (long)bi*256 + threadIdx.x;
    const int    cnt[6]  = {4096,16384,65536,4096,16384,131072};
    const int    nkA[6]  = {1,4,4,1,4,4};
    const int    tNA[6]  = {128,128,512,128,128,1024};
    const int    srcA[6] = {8,10,12,14,16,18};
    const size_t dstA[6] = {WS_WK1T,WS_WK2T,WS_WK3T,WS_WV1T,WS_WV2T,WS_WV3T};
    for(int s=0;s<6;s++){
      if(g < cnt[s]){
        int nk = nkA[s], tN = tNA[s];
        int i = (int)(g & 7), l = (int)((g>>3) & 63);
        int r2 = (int)(g >> 9);
        int kk = r2 % nk, c16 = r2 / nk;
        int n = c16*16 + (l & 15);
        int k = kk*32 + (l >> 4)*8 + i;
        ((u16*)(ws+dstA[s]))[g] = f2b(loadf(in.p[srcA[s]], (long)k*tN + n, isbf));
        return;
      }
      g -= cnt[s];
    }
    return;
  }
  // ---- tq ----
  __shared__ float sWin[1024];
  __shared__ float sWq[128];
  __shared__ float sN[1024];
  __shared__ float sT[256];
  float* t_ws = (float*)(ws+WS_T);
  float* q_ws = (float*)(ws+WS_Q);
  int tid = threadIdx.x;
  for(int i=tid;i<1024;i+=256) sWin[i] = loadf(in.p[4], i, isbf);
  if(tid<128) sWq[tid] = loadf(in.p[5], tid, isbf);
  int n0 = (bi - 928)*16;
  for(int i=tid;i<1024;i+=256) sN[i] = loadf(in.p[0], (long)n0*64 + i, isbf);
  __syncthreads();
  int ni = tid>>4, j = tid&15;
  float acc = 0.f;
  #pragma unroll 8
  for(int i=0;i<64;i++) acc += sN[ni*64+i]*sWin[i*16+j];
  float t = acc*0.125f;
  t_ws[(n0+ni)*16+j] = t;
  sT[tid] = t;
  __syncthreads();
  if(tid<128){
    int n2 = tid>>3, b = tid&7;
    float a2 = 0.f;
    #pragma unroll
    for(int jj=0;jj<16;jj++) a2 += sT[n2*16+jj]*sWq[jj*8+b];
    q_ws[(n0+n2)*8+b] = a2*0.25f;
  }
}

// ---------------- k_edges (r3 structure, 37888 B LDS, 4 blocks/CU) ----------------
__global__ __launch_bounds__(256,4) void k_edges(InP in, char* ws){
  const int isbf = detect_isbf(in.p[2]);
  const int* ei = (const int*)in.p[1];
  const float* t_ws = (const float*)(ws + WS_T);
  const float* q_ws = (const float*)(ws + WS_Q);
  float* Zp  = (float*)(ws + WS_Z);
  float* AGG = (float*)(ws + WS_AGG);

  __shared__ __align__(16) char smem[37888];
  u16*   sTSH = (u16*)smem;              // [64 e][20] bf16: 16 ts + 4 sh (2560 B)
  u16*   sH1  = (u16*)(smem + 2560);     // frag-packed [4 et][4 kk][512] (16384 B)
  u16*   sH2  = (u16*)(smem + 18944);    // (16384 B)
  float* sK   = (float*)(smem + 35328);  // [64][8] f32 (2048 B)
  float* sP   = (float*)(smem + 37376);  // [64] (256 B)
  int*   sDst = (int*)(smem + 37632);    // [64] (256 B)
  float* sV   = (float*)(smem + 2560);   // [64][16] f32, overlay on sH1 (dead by matvecV)

  const int tid  = threadIdx.x;
  const int e0   = blockIdx.x * 64;
  const int lane = tid & 63, wv = tid >> 6;
  const int lrow = lane & 15, lquad = lane >> 4;

  // ---- staging: ts gather + sh -> sTSH (bf16); zero sK ----
  {
    int e = tid >> 2, g4 = tid & 3;
    int src = ei[e0 + e];
    f32x4 tv = *(const f32x4*)&t_ws[src*16 + g4*4];
    u16x4 pk;
    #pragma unroll
    for(int r=0;r<4;r++) pk[r] = f2b(tv[r]);
    *(u16x4*)&sTSH[e*20 + g4*4] = pk;
    sTSH[e*20 + 16 + g4] = f2b(loadf(in.p[3], (long)(e0+e)*4 + g4, isbf));
  }
  for(int idx = tid; idx < 512; idx += 256) sK[idx] = 0.f;
  __syncthreads();

  // store D tile as next layer's frag-packed A (r3-verbatim)
  auto hstore = [&](u16* O, int et, int nt, const f32x4& c, const f32x4& bb){
    u16x4 pk;
    #pragma unroll
    for(int r=0;r<4;r++){
      float h = c[r] + bb[r];
      h = h > 0.f ? h : 0.f;
      pk[r] = f2b(h);
    }
    int off = et*2048 + (wv<<9) + (nt*2 + (lquad>>1))*128 + lrow*8 + (lquad&1)*4;
    *(u16x4*)&O[off] = pk;
  };

  // dense layer 1: A fragment direct from global edge_data (K=32)
  auto dense1g = [&](const u16* Wg, const void* biasp, u16* O){
    bf16x8 bw[2]; f32x4 bb[2];
    #pragma unroll
    for(int nt=0;nt<2;nt++){
      bw[nt] = ld8(&Wg[((wv*2+nt)<<9) + lane*8]);
      bb[nt] = loadf4(biasp, wv*32 + nt*16 + lquad*4, isbf);
    }
    #pragma unroll
    for(int et=0;et<4;et++){
      bf16x8 af;
      long base = (long)(e0 + et*16 + lrow)*32 + lquad*8;
      if(isbf){
        af = ld8((const u16*)in.p[2] + base);
      } else {
        const float* fp = (const float*)in.p[2] + base;
        f32x4 a = *(const f32x4*)fp, b = *(const f32x4*)(fp+4);
        u32 w0 = (u32)f2b(a[0]) | ((u32)f2b(a[1])<<16);
        u32 w1 = (u32)f2b(a[2]) | ((u32)f2b(a[3])<<16);
        u32 w2 = (u32)f2b(b[0]) | ((u32)f2b(b[1])<<16);
        u32 w3 = (u32)f2b(b[2]) | ((u32)f2b(b[3])<<16);
        uint4 v; v.x=w0; v.y=w1; v.z=w2; v.w=w3;
        af = __builtin_bit_cast(bf16x8, v);
      }
      #pragma unroll
      for(int nt=0;nt<2;nt++){
        f32x4 c = {0.f,0.f,0.f,0.f};
        c = __builtin_amdgcn_mfma_f32_16x16x32_bf16(bw[nt], af, c, 0, 0, 0);
        hstore(O, et, nt, c, bb[nt]);
      }
    }
  };

  // dense layer 2 (K=128), r3-verbatim
  auto dense2 = [&](const u16* A, const u16* Wg, const void* biasp, u16* O){
    bf16x8 bw[2][4]; f32x4 bb[2];
    #pragma unroll
    for(int nt=0;nt<2;nt++){
      #pragma unroll
      for(int kk=0;kk<4;kk++)
        bw[nt][kk] = ld8(&Wg[(((wv*2+nt)*4 + kk)<<9) + lane*8]);
      bb[nt] = loadf4(biasp, wv*32 + nt*16 + lquad*4, isbf);
    }
    #pragma unroll
    for(int et=0;et<4;et++){
      bf16x8 af[4];
      #pragma unroll
      for(int kk=0;kk<4;kk++) af[kk] = ld8(&A[et*2048 + (kk<<9) + lane*8]);
      #pragma unroll
      for(int nt=0;nt<2;nt++){
        f32x4 c = {0.f,0.f,0.f,0.f};
        #pragma unroll
        for(int kk=0;kk<4;kk++)
          c = __builtin_amdgcn_mfma_f32_16x16x32_bf16(bw[nt][kk], af[kk], c, 0, 0, 0);
        hstore(O, et, nt, c, bb[nt]);
      }
    }
  };

  // matvec + contract: ring parity is ALWAYS even at chunk entry (2 toggles/chunk)
  auto matvec = [&](const u16* Wg, const void* biasp, int NJ, int isval){
    float kp[16];
    #pragma unroll
    for(int i=0;i<16;i++) kp[i]=0.f;
    const int c0 = wv*NJ;
    bf16x8 bw[2][4]; f32x4 bb[2];
    #pragma unroll
    for(int kk=0;kk<4;kk++)
      bw[0][kk] = ld8(&Wg[(((c0*2)*4 + kk)<<9) + lane*8]);
    bb[0] = loadf4(biasp, c0*32 + lquad*4, isbf);
    for(int j=0;j<NJ;j++){
      int cur = 0, nxt = 1;                 // FIX(r6 bug): was j&1; ring is even at chunk entry
      for(int nt=0;nt<2;nt++){
        // prefetch the NEXT 16-col group's weights (ring of 2 half-chunks)
        if(nt==0){
          #pragma unroll
          for(int kk=0;kk<4;kk++)
            bw[nxt][kk] = ld8(&Wg[((((c0+j)*2+1)*4 + kk)<<9) + lane*8]);
          bb[nxt] = loadf4(biasp, (c0+j)*32 + 16 + lquad*4, isbf);
        } else if(j+1 < NJ){
          #pragma unroll
          for(int kk=0;kk<4;kk++)
            bw[nxt][kk] = ld8(&Wg[((((c0+j+1)*2)*4 + kk)<<9) + lane*8]);
          bb[nxt] = loadf4(biasp, (c0+j+1)*32 + lquad*4, isbf);
        }
        for(int et=0;et<4;et++){
          bf16x8 af[4];
          #pragma unroll
          for(int kk=0;kk<4;kk++)
            af[kk] = ld8(&sH2[et*2048 + (kk<<9) + lane*8]);
          const int e = et*16 + lrow;
          f32x4 c = {0.f,0.f,0.f,0.f};
          #pragma unroll
          for(int kk=0;kk<4;kk++)
            c = __builtin_amdgcn_mfma_f32_16x16x32_bf16(bw[cur][kk], af[kk], c, 0, 0, 0);
          int n0 = (c0+j)*32 + nt*16 + lquad*4;
          int as = isval ? (n0>>4) : (n0>>3);       // as = a*4+s for both layouts
          float pv = b2f(sTSH[e*20 + (as>>2)]) * b2f(sTSH[e*20 + 16 + (as&3)]);
          #pragma unroll
          for(int r=0;r<4;r++)
            kp[et*4+r] += pv * (c[r] + bb[cur][r]);
        }
        // swap ring
        cur ^= 1; nxt ^= 1;
      }
    }
    if(isval){
      #pragma unroll
      for(int et=0;et<4;et++){
        int e = et*16 + lrow;
        #pragma unroll
        for(int r=0;r<4;r++)
          atomicAdd(&sV[e*16 + lquad*4 + r], kp[et*4+r]*0.125f);
      }
    } else {
      int b0 = (lquad & 1)*4;
      #pragma unroll
      for(int et=0;et<4;et++){
        int e = et*16 + lrow;
        #pragma unroll
        for(int r=0;r<4;r++)
          atomicAdd(&sK[e*8 + b0 + r], kp[et*4+r]*0.125f);
      }
    }
  };

  // ---- K chain ----
  dense1g((const u16*)(ws+WS_WK1T), in.p[9], sH1);  __syncthreads();
  dense2(sH1, (const u16*)(ws+WS_WK2T), in.p[11], sH2); __syncthreads();
  matvec((const u16*)(ws+WS_WK3T), in.p[13], 4, 0);

  // ---- V chain ----
  dense1g((const u16*)(ws+WS_WV1T), in.p[15], sH1); __syncthreads();
  dense2(sH1, (const u16*)(ws+WS_WV2T), in.p[17], sH2); __syncthreads();
  // sH1 now dead: zero sV overlay
  for(int idx = tid; idx < 1024; idx += 256) sV[idx] = 0.f;
  __syncthreads();
  matvec((const u16*)(ws+WS_WV3T), in.p[19], 8, 1);
  __syncthreads();

  // ---- tail: logit + exp + z (wave 0), then p*v -> AGG ----
  if(wv == 0){
    int mydst = ei[N_EDGES + e0 + lane];
    float acc = 0.f;
    #pragma unroll
    for(int a=0;a<8;a++){
      float qa = q_ws[mydst*8 + a];
      #pragma unroll
      for(int b=0;b<8;b++)
        acc += qa * loadf(in.p[6], a*8+b, isbf) * sK[lane*8+b];
    }
    float p = __expf(acc * 0.125f);    // softmax shift-invariant; logits O(1)
    atomicAdd(Zp + mydst, p);
    sP[lane] = p;
    sDst[lane] = mydst;
  }
  __syncthreads();
  for(int idx = tid; idx < 1024; idx += 256){
    int e = idx >> 4;
    atomicAdd(AGG + (long)sDst[e]*16 + (idx & 15), sP[e]*sV[idx]);
  }
}

// ---------------- out-linear + residual + BN partials ----------------
__global__ void k7a(InP in, char* ws){
  const int isbf = detect_isbf(in.p[2]);
  __shared__ float sWo[1024];
  __shared__ float ls[256], lq[256];
  int tid = threadIdx.x;
  for(int i=tid;i<1024;i+=256) sWo[i] = loadf(in.p[7], i, isbf);
  __syncthreads();
  const float* AGG = (const float*)(ws+WS_AGG);
  const float* Zp  = (const float*)(ws+WS_Z);
  float* OUTP = (float*)(ws+WS_OUTP);
  int c = tid & 63, r4 = tid >> 6;
  float s=0.f, q=0.f;
  for(int it=0; it<10; it++){
    int n = blockIdx.x*40 + it*4 + r4;       // 250 blocks * 40 = 10000
    float z = Zp[n];
    float inv = z > 0.f ? 0.25f/z : 0.f;
    const float* ag = AGG + (long)n*16;
    float acc = 0.f;
    #pragma unroll
    for(int j=0;j<16;j++) acc += ag[j]*sWo[j*64+c];
    float o = acc*inv + loadf(in.p[0], (long)n*64 + c, isbf);
    OUTP[(long)n*64+c] = o;
    s += o; q += o*o;
  }
  ls[tid]=s; lq[tid]=q;
  __syncthreads();
  if(tid < 64){
    float ss = ls[tid]+ls[tid+64]+ls[tid+128]+ls[tid+192];
    float qq = lq[tid]+lq[tid+64]+lq[tid+128]+lq[tid+192];
    atomicAdd((float*)(ws+WS_BNS)+tid, ss);
    atomicAdd((float*)(ws+WS_BNQ)+tid, qq);
  }
}

__global__ void k7c(InP in, char* ws, void* d_out){
  const int isbf = detect_isbf(in.p[2]);
  int idx = blockIdx.x*256 + threadIdx.x;
  if(idx >= N_NODES*64) return;
  int c = idx & 63;
  float s  = ((const float*)(ws+WS_BNS))[c];
  float qq = ((const float*)(ws+WS_BNQ))[c];
  float mean = s * (1.f/N_NODES);
  float var  = qq * (1.f/N_NODES) - mean*mean;
  float sc = rsqrtf(var + 1e-5f) * loadf(in.p[20], c, isbf);
  float val = (((const float*)(ws+WS_OUTP))[idx] - mean)*sc + loadf(in.p[21], c, isbf);
  if(isbf) ((u16*)d_out)[idx] = f2b(val);
  else     ((float*)d_out)[idx] = val;
}

extern "C" void kernel_launch(void* const* d_in, const int* in_sizes, int n_in,
                              void* d_out, int out_size, void* d_ws, size_t ws_size,
                              hipStream_t stream){
  InP in;
  for(int i=0;i<22;i++) in.p[i] = d_in[i];
  char* ws = (char*)d_ws;

  hipMemsetAsync(ws + ZERO_OFF, 0, ZERO_LEN, stream);
  k_pre<<<1553,256,0,stream>>>(in, ws);
  k_edges<<<2500,256,0,stream>>>(in, ws);
  k7a<<<250,256,0,stream>>>(in, ws);
  k7c<<<2500,256,0,stream>>>(in, ws, d_out);
}

// Round 8
// 437.557 us; speedup vs baseline: 1.5696x; 1.5696x over previous
//
#include <hip/hip_runtime.h>

#define N_NODES 10000
#define N_EDGES 160000

typedef unsigned short u16;
typedef unsigned int   u32;
typedef __bf16 bf16x8 __attribute__((ext_vector_type(8)));
typedef float  f32x4  __attribute__((ext_vector_type(4)));
typedef unsigned short u16x4 __attribute__((ext_vector_type(4)));

struct InP { const void* p[22]; };

// ---------------- workspace layout (bytes) ----------------
static constexpr size_t WS_WK1T = 0;                        // bf16 4096  frag-packed
static constexpr size_t WS_WK2T = WS_WK1T + 8192;           // bf16 16384
static constexpr size_t WS_WK3T = WS_WK2T + 32768;          // bf16 65536
static constexpr size_t WS_WV1T = WS_WK3T + 131072;         // bf16 4096
static constexpr size_t WS_WV2T = WS_WV1T + 8192;           // bf16 16384
static constexpr size_t WS_WV3T = WS_WV2T + 32768;          // bf16 131072
static constexpr size_t WS_T    = WS_WV3T + 262144;         // f32 [N][16]
static constexpr size_t WS_Q    = WS_T    + (size_t)N_NODES*16*4;  // f32 [N][8]
static constexpr size_t WS_Z    = WS_Q    + (size_t)N_NODES*8*4;   // f32 [N]
static constexpr size_t WS_AGG  = WS_Z    + (size_t)N_NODES*4;     // f32 [N][16]
static constexpr size_t WS_BNS  = WS_AGG  + (size_t)N_NODES*16*4;  // f32 64
static constexpr size_t WS_BNQ  = WS_BNS  + 256;
static constexpr size_t WS_OUTP = WS_BNQ  + 256;            // f32 [N][64]
static constexpr size_t ZERO_OFF = WS_Z;
static constexpr size_t ZERO_LEN = WS_OUTP - WS_Z;

// ---------------- helpers ----------------
__device__ __forceinline__ int detect_isbf(const void* ed){
  int lane = threadIdx.x & 63;
  u16 v = ((const u16*)ed)[lane*2];
  int ex = (v >> 7) & 0xFF;
  unsigned long long b = __ballot(ex >= 100 && ex <= 140);
  return __popcll(b) >= 48;
}
__device__ __forceinline__ float loadf(const void* p, long i, int isbf){
  if(isbf){
    u32 x = ((u32)((const u16*)p)[i]) << 16;
    return __uint_as_float(x);
  }
  return ((const float*)p)[i];
}
__device__ __forceinline__ f32x4 loadf4(const void* p, long i, int isbf){
  if(isbf){
    u16x4 v = *(const u16x4*)((const u16*)p + i);
    f32x4 r;
    #pragma unroll
    for(int k=0;k<4;k++) r[k] = __uint_as_float(((u32)v[k])<<16);
    return r;
  }
  return *(const f32x4*)((const float*)p + i);
}
__device__ __forceinline__ u16 f2b(float f){
  u32 u = __float_as_uint(f);
  u += 0x7fffu + ((u >> 16) & 1u);
  return (u16)(u >> 16);
}
__device__ __forceinline__ float b2f(u16 v){
  return __uint_as_float(((u32)v) << 16);
}
__device__ __forceinline__ bf16x8 ld8(const u16* p){
  uint4 v = *(const uint4*)p;
  return __builtin_bit_cast(bf16x8, v);
}

// ---------------- k_pre: weight frag-packing + per-node t/q ----------------
// phys g: i=g&7; l=(g>>3)&63; r2=g>>9; kk=r2%nk; c16=r2/nk;
// n=c16*16+(l&15); k=kk*32+(l>>4)*8+i; src=W[k][n]   (r3-verified)
__global__ void k_pre(InP in, char* ws){
  const int isbf = detect_isbf(in.p[2]);
  int bi = blockIdx.x;
  if(bi < 928){
    long g = (long)bi*256 + threadIdx.x;
    const int    cnt[6]  = {4096,16384,65536,4096,16384,131072};
    const int    nkA[6]  = {1,4,4,1,4,4};
    const int    tNA[6]  = {128,128,512,128,128,1024};
    const int    srcA[6] = {8,10,12,14,16,18};
    const size_t dstA[6] = {WS_WK1T,WS_WK2T,WS_WK3T,WS_WV1T,WS_WV2T,WS_WV3T};
    for(int s=0;s<6;s++){
      if(g < cnt[s]){
        int nk = nkA[s], tN = tNA[s];
        int i = (int)(g & 7), l = (int)((g>>3) & 63);
        int r2 = (int)(g >> 9);
        int kk = r2 % nk, c16 = r2 / nk;
        int n = c16*16 + (l & 15);
        int k = kk*32 + (l >> 4)*8 + i;
        ((u16*)(ws+dstA[s]))[g] = f2b(loadf(in.p[srcA[s]], (long)k*tN + n, isbf));
        return;
      }
      g -= cnt[s];
    }
    return;
  }
  // ---- tq ----
  __shared__ float sWin[1024];
  __shared__ float sWq[128];
  __shared__ float sN[1024];
  __shared__ float sT[256];
  float* t_ws = (float*)(ws+WS_T);
  float* q_ws = (float*)(ws+WS_Q);
  int tid = threadIdx.x;
  for(int i=tid;i<1024;i+=256) sWin[i] = loadf(in.p[4], i, isbf);
  if(tid<128) sWq[tid] = loadf(in.p[5], tid, isbf);
  int n0 = (bi - 928)*16;
  for(int i=tid;i<1024;i+=256) sN[i] = loadf(in.p[0], (long)n0*64 + i, isbf);
  __syncthreads();
  int ni = tid>>4, j = tid&15;
  float acc = 0.f;
  #pragma unroll 8
  for(int i=0;i<64;i++) acc += sN[ni*64+i]*sWin[i*16+j];
  float t = acc*0.125f;
  t_ws[(n0+ni)*16+j] = t;
  sT[tid] = t;
  __syncthreads();
  if(tid<128){
    int n2 = tid>>3, b = tid&7;
    float a2 = 0.f;
    #pragma unroll
    for(int jj=0;jj<16;jj++) a2 += sT[n2*16+jj]*sWq[jj*8+b];
    q_ws[(n0+n2)*8+b] = a2*0.25f;
  }
}

// ---------------- k_edges (r7 layout, 37888 B LDS; (256,3) reg cap -> no spill) ----------------
__global__ __launch_bounds__(256,3) void k_edges(InP in, char* ws){
  const int isbf = detect_isbf(in.p[2]);
  const int* ei = (const int*)in.p[1];
  const float* t_ws = (const float*)(ws + WS_T);
  const float* q_ws = (const float*)(ws + WS_Q);
  float* Zp  = (float*)(ws + WS_Z);
  float* AGG = (float*)(ws + WS_AGG);

  __shared__ __align__(16) char smem[37888];
  u16*   sTSH = (u16*)smem;              // [64 e][20] bf16: 16 ts + 4 sh (2560 B)
  u16*   sH1  = (u16*)(smem + 2560);     // frag-packed [4 et][4 kk][512] (16384 B)
  u16*   sH2  = (u16*)(smem + 18944);    // (16384 B)
  float* sK   = (float*)(smem + 35328);  // [64][8] f32 (2048 B)
  float* sP   = (float*)(smem + 37376);  // [64] (256 B)
  int*   sDst = (int*)(smem + 37632);    // [64] (256 B)
  float* sV   = (float*)(smem + 2560);   // [64][16] f32, overlay on sH1 (dead by matvecV)

  const int tid  = threadIdx.x;
  const int e0   = blockIdx.x * 64;
  const int lane = tid & 63, wv = tid >> 6;
  const int lrow = lane & 15, lquad = lane >> 4;

  // ---- staging: ts gather + sh -> sTSH (bf16); zero sK ----
  {
    int e = tid >> 2, g4 = tid & 3;
    int src = ei[e0 + e];
    f32x4 tv = *(const f32x4*)&t_ws[src*16 + g4*4];
    u16x4 pk;
    #pragma unroll
    for(int r=0;r<4;r++) pk[r] = f2b(tv[r]);
    *(u16x4*)&sTSH[e*20 + g4*4] = pk;
    sTSH[e*20 + 16 + g4] = f2b(loadf(in.p[3], (long)(e0+e)*4 + g4, isbf));
  }
  for(int idx = tid; idx < 512; idx += 256) sK[idx] = 0.f;
  __syncthreads();

  // store D tile as next layer's frag-packed A (r3-verbatim)
  auto hstore = [&](u16* O, int et, int nt, const f32x4& c, const f32x4& bb){
    u16x4 pk;
    #pragma unroll
    for(int r=0;r<4;r++){
      float h = c[r] + bb[r];
      h = h > 0.f ? h : 0.f;
      pk[r] = f2b(h);
    }
    int off = et*2048 + (wv<<9) + (nt*2 + (lquad>>1))*128 + lrow*8 + (lquad&1)*4;
    *(u16x4*)&O[off] = pk;
  };

  // dense layer 1: A fragment direct from global edge_data (K=32)
  auto dense1g = [&](const u16* Wg, const void* biasp, u16* O){
    bf16x8 bw[2]; f32x4 bb[2];
    #pragma unroll
    for(int nt=0;nt<2;nt++){
      bw[nt] = ld8(&Wg[((wv*2+nt)<<9) + lane*8]);
      bb[nt] = loadf4(biasp, wv*32 + nt*16 + lquad*4, isbf);
    }
    #pragma unroll
    for(int et=0;et<4;et++){
      bf16x8 af;
      long base = (long)(e0 + et*16 + lrow)*32 + lquad*8;
      if(isbf){
        af = ld8((const u16*)in.p[2] + base);
      } else {
        const float* fp = (const float*)in.p[2] + base;
        f32x4 a = *(const f32x4*)fp, b = *(const f32x4*)(fp+4);
        u32 w0 = (u32)f2b(a[0]) | ((u32)f2b(a[1])<<16);
        u32 w1 = (u32)f2b(a[2]) | ((u32)f2b(a[3])<<16);
        u32 w2 = (u32)f2b(b[0]) | ((u32)f2b(b[1])<<16);
        u32 w3 = (u32)f2b(b[2]) | ((u32)f2b(b[3])<<16);
        uint4 v; v.x=w0; v.y=w1; v.z=w2; v.w=w3;
        af = __builtin_bit_cast(bf16x8, v);
      }
      #pragma unroll
      for(int nt=0;nt<2;nt++){
        f32x4 c = {0.f,0.f,0.f,0.f};
        c = __builtin_amdgcn_mfma_f32_16x16x32_bf16(bw[nt], af, c, 0, 0, 0);
        hstore(O, et, nt, c, bb[nt]);
      }
    }
  };

  // dense layer 2 (K=128), r3-verbatim
  auto dense2 = [&](const u16* A, const u16* Wg, const void* biasp, u16* O){
    bf16x8 bw[2][4]; f32x4 bb[2];
    #pragma unroll
    for(int nt=0;nt<2;nt++){
      #pragma unroll
      for(int kk=0;kk<4;kk++)
        bw[nt][kk] = ld8(&Wg[(((wv*2+nt)*4 + kk)<<9) + lane*8]);
      bb[nt] = loadf4(biasp, wv*32 + nt*16 + lquad*4, isbf);
    }
    #pragma unroll
    for(int et=0;et<4;et++){
      bf16x8 af[4];
      #pragma unroll
      for(int kk=0;kk<4;kk++) af[kk] = ld8(&A[et*2048 + (kk<<9) + lane*8]);
      #pragma unroll
      for(int nt=0;nt<2;nt++){
        f32x4 c = {0.f,0.f,0.f,0.f};
        #pragma unroll
        for(int kk=0;kk<4;kk++)
          c = __builtin_amdgcn_mfma_f32_16x16x32_bf16(bw[nt][kk], af[kk], c, 0, 0, 0);
        hstore(O, et, nt, c, bb[nt]);
      }
    }
  };

  // matvec + contract: ring parity is ALWAYS even at chunk entry (2 toggles/chunk)
  auto matvec = [&](const u16* Wg, const void* biasp, int NJ, int isval){
    float kp[16];
    #pragma unroll
    for(int i=0;i<16;i++) kp[i]=0.f;
    const int c0 = wv*NJ;
    bf16x8 bw[2][4]; f32x4 bb[2];
    #pragma unroll
    for(int kk=0;kk<4;kk++)
      bw[0][kk] = ld8(&Wg[(((c0*2)*4 + kk)<<9) + lane*8]);
    bb[0] = loadf4(biasp, c0*32 + lquad*4, isbf);
    for(int j=0;j<NJ;j++){
      int cur = 0, nxt = 1;                 // ring is even at chunk entry
      for(int nt=0;nt<2;nt++){
        // prefetch the NEXT 16-col group's weights (ring of 2 half-chunks)
        if(nt==0){
          #pragma unroll
          for(int kk=0;kk<4;kk++)
            bw[nxt][kk] = ld8(&Wg[((((c0+j)*2+1)*4 + kk)<<9) + lane*8]);
          bb[nxt] = loadf4(biasp, (c0+j)*32 + 16 + lquad*4, isbf);
        } else if(j+1 < NJ){
          #pragma unroll
          for(int kk=0;kk<4;kk++)
            bw[nxt][kk] = ld8(&Wg[((((c0+j+1)*2)*4 + kk)<<9) + lane*8]);
          bb[nxt] = loadf4(biasp, (c0+j+1)*32 + lquad*4, isbf);
        }
        for(int et=0;et<4;et++){
          bf16x8 af[4];
          #pragma unroll
          for(int kk=0;kk<4;kk++)
            af[kk] = ld8(&sH2[et*2048 + (kk<<9) + lane*8]);
          const int e = et*16 + lrow;
          f32x4 c = {0.f,0.f,0.f,0.f};
          #pragma unroll
          for(int kk=0;kk<4;kk++)
            c = __builtin_amdgcn_mfma_f32_16x16x32_bf16(bw[cur][kk], af[kk], c, 0, 0, 0);
          int n0 = (c0+j)*32 + nt*16 + lquad*4;
          int as = isval ? (n0>>4) : (n0>>3);       // as = a*4+s for both layouts
          float pv = b2f(sTSH[e*20 + (as>>2)]) * b2f(sTSH[e*20 + 16 + (as&3)]);
          #pragma unroll
          for(int r=0;r<4;r++)
            kp[et*4+r] += pv * (c[r] + bb[cur][r]);
        }
        // swap ring
        cur ^= 1; nxt ^= 1;
      }
    }
    if(isval){
      #pragma unroll
      for(int et=0;et<4;et++){
        int e = et*16 + lrow;
        #pragma unroll
        for(int r=0;r<4;r++)
          atomicAdd(&sV[e*16 + lquad*4 + r], kp[et*4+r]*0.125f);
      }
    } else {
      int b0 = (lquad & 1)*4;
      #pragma unroll
      for(int et=0;et<4;et++){
        int e = et*16 + lrow;
        #pragma unroll
        for(int r=0;r<4;r++)
          atomicAdd(&sK[e*8 + b0 + r], kp[et*4+r]*0.125f);
      }
    }
  };

  // ---- K chain ----
  dense1g((const u16*)(ws+WS_WK1T), in.p[9], sH1);  __syncthreads();
  dense2(sH1, (const u16*)(ws+WS_WK2T), in.p[11], sH2); __syncthreads();
  matvec((const u16*)(ws+WS_WK3T), in.p[13], 4, 0);

  // ---- V chain ----
  dense1g((const u16*)(ws+WS_WV1T), in.p[15], sH1); __syncthreads();
  dense2(sH1, (const u16*)(ws+WS_WV2T), in.p[17], sH2); __syncthreads();
  // sH1 now dead: zero sV overlay
  for(int idx = tid; idx < 1024; idx += 256) sV[idx] = 0.f;
  __syncthreads();
  matvec((const u16*)(ws+WS_WV3T), in.p[19], 8, 1);
  __syncthreads();

  // ---- tail: logit + exp + z (wave 0), then p*v -> AGG ----
  if(wv == 0){
    int mydst = ei[N_EDGES + e0 + lane];
    float acc = 0.f;
    #pragma unroll
    for(int a=0;a<8;a++){
      float qa = q_ws[mydst*8 + a];
      #pragma unroll
      for(int b=0;b<8;b++)
        acc += qa * loadf(in.p[6], a*8+b, isbf) * sK[lane*8+b];
    }
    float p = __expf(acc * 0.125f);    // softmax shift-invariant; logits O(1)
    atomicAdd(Zp + mydst, p);
    sP[lane] = p;
    sDst[lane] = mydst;
  }
  __syncthreads();
  for(int idx = tid; idx < 1024; idx += 256){
    int e = idx >> 4;
    atomicAdd(AGG + (long)sDst[e]*16 + (idx & 15), sP[e]*sV[idx]);
  }
}

// ---------------- out-linear + residual + BN partials ----------------
__global__ void k7a(InP in, char* ws){
  const int isbf = detect_isbf(in.p[2]);
  __shared__ float sWo[1024];
  __shared__ float ls[256], lq[256];
  int tid = threadIdx.x;
  for(int i=tid;i<1024;i+=256) sWo[i] = loadf(in.p[7], i, isbf);
  __syncthreads();
  const float* AGG = (const float*)(ws+WS_AGG);
  const float* Zp  = (const float*)(ws+WS_Z);
  float* OUTP = (float*)(ws+WS_OUTP);
  int c = tid & 63, r4 = tid >> 6;
  float s=0.f, q=0.f;
  for(int it=0; it<10; it++){
    int n = blockIdx.x*40 + it*4 + r4;       // 250 blocks * 40 = 10000
    float z = Zp[n];
    float inv = z > 0.f ? 0.25f/z : 0.f;
    const float* ag = AGG + (long)n*16;
    float acc = 0.f;
    #pragma unroll
    for(int j=0;j<16;j++) acc += ag[j]*sWo[j*64+c];
    float o = acc*inv + loadf(in.p[0], (long)n*64 + c, isbf);
    OUTP[(long)n*64+c] = o;
    s += o; q += o*o;
  }
  ls[tid]=s; lq[tid]=q;
  __syncthreads();
  if(tid < 64){
    float ss = ls[tid]+ls[tid+64]+ls[tid+128]+ls[tid+192];
    float qq = lq[tid]+lq[tid+64]+lq[tid+128]+lq[tid+192];
    atomicAdd((float*)(ws+WS_BNS)+tid, ss);
    atomicAdd((float*)(ws+WS_BNQ)+tid, qq);
  }
}

__global__ void k7c(InP in, char* ws, void* d_out){
  const int isbf = detect_isbf(in.p[2]);
  int idx = blockIdx.x*256 + threadIdx.x;
  if(idx >= N_NODES*64) return;
  int c = idx & 63;
  float s  = ((const float*)(ws+WS_BNS))[c];
  float qq = ((const float*)(ws+WS_BNQ))[c];
  float mean = s * (1.f/N_NODES);
  float var  = qq * (1.f/N_NODES) - mean*mean;
  float sc = rsqrtf(var + 1e-5f) * loadf(in.p[20], c, isbf);
  float val = (((const float*)(ws+WS_OUTP))[idx] - mean)*sc + loadf(in.p[21], c, isbf);
  if(isbf) ((u16*)d_out)[idx] = f2b(val);
  else     ((float*)d_out)[idx] = val;
}

extern "C" void kernel_launch(void* const* d_in, const int* in_sizes, int n_in,
                              void* d_out, int out_size, void* d_ws, size_t ws_size,
                              hipStream_t stream){
  InP in;
  for(int i=0;i<22;i++) in.p[i] = d_in[i];
  char* ws = (char*)d_ws;

  hipMemsetAsync(ws + ZERO_OFF, 0, ZERO_LEN, stream);
  k_pre<<<1553,256,0,stream>>>(in, ws);
  k_edges<<<2500,256,0,stream>>>(in, ws);
  k7a<<<250,256,0,stream>>>(in, ws);
  k7c<<<2500,256,0,stream>>>(in, ws, d_out);
}